// Round 3
// baseline (1238.098 us; speedup 1.0000x reference)
//
#include <hip/hip_runtime.h>
#include <math.h>

#define DM 256          // d_model
#define NS 64           // N state
#define SP 128          // spatial H == W
#define KPAD 32         // zero-pad rows in front of kernel (for negative indices)
#define KROWS (KPAD + SP)   // 160

typedef __attribute__((ext_vector_type(8))) short bf16x8;
typedef __attribute__((ext_vector_type(4))) float f32x4;

__device__ __forceinline__ float gelu_f(float x) {
    float x3 = x * x * x;
    return 0.5f * x * (1.0f + tanhf(0.7978845608028654f * (x + 0.044715f * x3)));
}
__device__ __forceinline__ float sigmoid_f(float x) {
    return 1.0f / (1.0f + expf(-x));
}
__device__ __forceinline__ unsigned short f2bf(float f) {   // RNE f32->bf16
    unsigned u = __float_as_uint(f);
    u += 0x7fff + ((u >> 16) & 1);
    return (unsigned short)(u >> 16);
}
__device__ __forceinline__ float bf2f(unsigned short b) {
    return __uint_as_float(((unsigned)b) << 16);
}

// ---------------------------------------------------------------------------
// S4D kernel generation (verified round 1).
// ---------------------------------------------------------------------------
__global__ __launch_bounds__(128) void gen_k_kernel(
        const float* __restrict__ log_dt, const float* __restrict__ logA_re,
        const float* __restrict__ A_im,   const float* __restrict__ C_re,
        const float* __restrict__ C_im,   float* __restrict__ K_Tp) {
    int blk = blockIdx.x;
    int d  = blk & (DM - 1);
    int la = blk >> 8;
    int q  = threadIdx.x;
    __shared__ float s_cbr[NS], s_cbi[NS], s_dr[NS], s_di[NS];
    int pbase = (la * DM + d) * NS;
    float dt = expf(log_dt[la * DM + d]);
    if (q < NS) {
        int n = q;
        float ar = -expf(logA_re[pbase + n]);
        float ai = A_im[pbase + n];
        float dr = dt * ar, di = dt * ai;
        float er = expf(dr);
        float sn, cs;
        sincosf(di, &sn, &cs);
        float nr = er * cs - 1.0f, ni = er * sn;
        float inv = 1.0f / (ar * ar + ai * ai);
        float br = (nr * ar + ni * ai) * inv;
        float bi = (ni * ar - nr * ai) * inv;
        float cr = C_re[pbase + n], ci = C_im[pbase + n];
        s_cbr[n] = cr * br - ci * bi;
        s_cbi[n] = cr * bi + ci * br;
        s_dr[n] = dr;
        s_di[n] = di;
    }
    __syncthreads();
    float fq = (float)q;
    float acc = 0.0f;
    for (int n = 0; n < NS; ++n) {
        float pr = expf(s_dr[n] * fq);
        float sn, cs;
        sincosf(s_di[n] * fq, &sn, &cs);
        acc += s_cbr[n] * (pr * cs) - s_cbi[n] * (pr * sn);
    }
    K_Tp[(la * KROWS + KPAD + q) * DM + d] = 2.0f * acc;
}

// ---------------------------------------------------------------------------
// W_out fp32 [l][k=256][n=512]  ->  B_T bf16 [l][n=512][k=256]
// ---------------------------------------------------------------------------
__global__ __launch_bounds__(256) void prep_b_kernel(
        const float* __restrict__ Wo, unsigned short* __restrict__ Bt) {
    int idx = blockIdx.x * 256 + threadIdx.x;      // 4*512*256 total
    int l = idx >> 17, rem = idx & 131071, n = rem >> 8, k = rem & 255;
    Bt[idx] = f2bf(Wo[(size_t)l * 131072 + k * 512 + n]);
}

// ---------------------------------------------------------------------------
// Encoder (unchanged).
// ---------------------------------------------------------------------------
__global__ __launch_bounds__(256) void encode_kernel(
        const float* __restrict__ x, const float* __restrict__ g,
        const float* __restrict__ W_enc, const float* __restrict__ b_enc,
        float* __restrict__ h) {
    int total = 4 * SP * SP * DM;
    for (int idx = blockIdx.x * blockDim.x + threadIdx.x; idx < total;
         idx += gridDim.x * blockDim.x) {
        int d = idx & (DM - 1);
        int pos = idx >> 8;
        h[idx] = x[pos] * W_enc[d] + g[pos] * W_enc[DM + d] + b_enc[d];
    }
}

// ---------------------------------------------------------------------------
// Conv along W, (r, tile)-split: grid 2048 = r(512) x t(4). Thread = channel.
// Reads h fp32 (b,hh,w,d), writes T bf16 transposed (b,w,hh,d).
// ---------------------------------------------------------------------------
__global__ __launch_bounds__(256) void conv_w_kernel(
        const float* __restrict__ in, unsigned short* __restrict__ outT,
        const float* __restrict__ KT) {
    int bid = blockIdx.x;
    int r = bid >> 2, t = bid & 3;
    int tid = threadIdx.x;
    const float* row = in + (size_t)r * (SP * DM);
    int b = r >> 7, rr = r & 127;
    int w0 = t * 32;
    float acc[32], kreg[32];
    #pragma unroll
    for (int i = 0; i < 32; ++i) acc[i] = 0.0f;
    #pragma unroll
    for (int s = 0; s < 32; ++s) kreg[s] = KT[(KPAD + w0 + s) * DM + tid];
    for (int jb = 0; jb <= t; ++jb) {
        #pragma unroll
        for (int jj = 0; jj < 32; ++jj) {
            int j = jb * 32 + jj;
            float uj = row[j * DM + tid];
            float knew = KT[(KPAD + w0 - j - 1) * DM + tid];
            #pragma unroll
            for (int i = 0; i < 32; ++i)
                acc[i] = fmaf(kreg[(i - jj) & 31], uj, acc[i]);
            kreg[(31 - jj) & 31] = knew;
        }
    }
    #pragma unroll
    for (int i = 0; i < 32; ++i)
        outT[((size_t)((b << 7) | (w0 + i)) * SP + rr) * DM + tid] = f2bf(acc[i]);
}

// ---------------------------------------------------------------------------
// Conv along H, (r, tile)-split: grid 2048. Fuses gelu(conv + h*Dskip),
// writes bf16 A[m][k], m=(b,w,hh).
// ---------------------------------------------------------------------------
__global__ __launch_bounds__(256) void conv_h_kernel(
        const unsigned short* __restrict__ inT, unsigned short* __restrict__ outA,
        const float* __restrict__ KT,
        const float* __restrict__ h, const float* __restrict__ Dsk) {
    int bid = blockIdx.x;
    int r = bid >> 2, t = bid & 3;
    int tid = threadIdx.x;
    const unsigned short* row = inT + (size_t)r * (SP * DM);
    int b = r >> 7, rr = r & 127;  // rr = w
    float dk = Dsk[tid];
    int w0 = t * 32;
    float acc[32], kreg[32];
    #pragma unroll
    for (int i = 0; i < 32; ++i) acc[i] = 0.0f;
    #pragma unroll
    for (int s = 0; s < 32; ++s) kreg[s] = KT[(KPAD + w0 + s) * DM + tid];
    for (int jb = 0; jb <= t; ++jb) {
        #pragma unroll
        for (int jj = 0; jj < 32; ++jj) {
            int j = jb * 32 + jj;
            float uj = bf2f(row[j * DM + tid]);
            float knew = KT[(KPAD + w0 - j - 1) * DM + tid];
            #pragma unroll
            for (int i = 0; i < 32; ++i)
                acc[i] = fmaf(kreg[(i - jj) & 31], uj, acc[i]);
            kreg[(31 - jj) & 31] = knew;
        }
    }
    #pragma unroll
    for (int i = 0; i < 32; ++i) {
        int hh = w0 + i;
        size_t hoff = ((size_t)((b << 14) | (hh << 7) | rr)) * DM + tid;
        float val = fmaf(h[hoff], dk, acc[i]);
        outA[((size_t)r * SP + hh) * DM + tid] = f2bf(gelu_f(val));
    }
}

// ---------------------------------------------------------------------------
// g-pass: G = sigmoid(A @ W_g + b_g), stored bf16 in MFMA-frag layout.
// Persistent W-in-registers: wave holds 64 W-cols x K=256 (32 bf16x8 = 128 VGPR).
// Swapped operands: mfma(w_frag, act_frag, acc) -> D[wcol][actrow],
// lane: actrow = lane&15, wcols = (lane>>4)*4+reg per mf.
// grid 256 blocks x 512 thr (8 waves: cg = wv&3, sgrp = wv>>2), 8 strips/wave.
// ---------------------------------------------------------------------------
__global__ __launch_bounds__(512, 2) void gpass_kernel(
        const unsigned short* __restrict__ Ab, const unsigned short* __restrict__ Bt,
        const float* __restrict__ bo, unsigned short* __restrict__ G) {
    int tid = threadIdx.x;
    int lane = tid & 63, wv = tid >> 6;
    int cg = wv & 3, sgrp = wv >> 2;
    int lc = lane & 15, g = lane >> 4;

    bf16x8 wf[4][8];
    #pragma unroll
    for (int mf = 0; mf < 4; ++mf)
        #pragma unroll
        for (int kk = 0; kk < 8; ++kk)
            wf[mf][kk] = *(const bf16x8*)(Bt + (size_t)(256 + cg * 64 + mf * 16 + lc) * DM + kk * 32 + g * 8);

    float4 bb[4];
    #pragma unroll
    for (int mf = 0; mf < 4; ++mf)
        bb[mf] = *(const float4*)(bo + 256 + cg * 64 + mf * 16 + g * 4);

    int s0 = blockIdx.x * 16 + sgrp;
    bf16x8 af[8];
    #pragma unroll
    for (int kk = 0; kk < 8; ++kk)
        af[kk] = *(const bf16x8*)(Ab + (size_t)(s0 * 16 + lc) * DM + kk * 32 + g * 8);

    #pragma unroll
    for (int it = 0; it < 8; ++it) {
        int s = s0 + it * 2;
        f32x4 acc[4];
        #pragma unroll
        for (int mf = 0; mf < 4; ++mf) acc[mf] = (f32x4){0.f, 0.f, 0.f, 0.f};
        #pragma unroll
        for (int kk = 0; kk < 8; ++kk)
            #pragma unroll
            for (int mf = 0; mf < 4; ++mf)
                acc[mf] = __builtin_amdgcn_mfma_f32_16x16x32_bf16(wf[mf][kk], af[kk], acc[mf], 0, 0, 0);
        if (it < 7) {
            int sn = s + 2;
            #pragma unroll
            for (int kk = 0; kk < 8; ++kk)
                af[kk] = *(const bf16x8*)(Ab + (size_t)(sn * 16 + lc) * DM + kk * 32 + g * 8);
        }
        #pragma unroll
        for (int mf = 0; mf < 4; ++mf) {
            ushort4 o;
            o.x = f2bf(sigmoid_f(acc[mf][0] + bb[mf].x));
            o.y = f2bf(sigmoid_f(acc[mf][1] + bb[mf].y));
            o.z = f2bf(sigmoid_f(acc[mf][2] + bb[mf].z));
            o.w = f2bf(sigmoid_f(acc[mf][3] + bb[mf].w));
            *(ushort4*)(G + ((size_t)((s * 4 + cg) * 4 + mf) * 64 + lane) * 4) = o;
        }
    }
}

// ---------------------------------------------------------------------------
// a-pass: a = A @ W_a + b_a; y = a * G; + h residual; LayerNorm -> h in place.
// Same persistent-W structure. Lockstep strip iterations with 2 barriers for
// the cross-cg LN combine (pads 1KB LDS).
// ---------------------------------------------------------------------------
__global__ __launch_bounds__(512, 2) void apass_kernel(
        const unsigned short* __restrict__ Ab, const unsigned short* __restrict__ Bt,
        const unsigned short* __restrict__ G, float* __restrict__ h,
        const float* __restrict__ bo, const float* __restrict__ lnw,
        const float* __restrict__ lnb) {
    __shared__ float pads[2][16][4][2];
    int tid = threadIdx.x;
    int lane = tid & 63, wv = tid >> 6;
    int cg = wv & 3, sgrp = wv >> 2;
    int lc = lane & 15, g = lane >> 4;

    bf16x8 wf[4][8];
    #pragma unroll
    for (int mf = 0; mf < 4; ++mf)
        #pragma unroll
        for (int kk = 0; kk < 8; ++kk)
            wf[mf][kk] = *(const bf16x8*)(Bt + (size_t)(cg * 64 + mf * 16 + lc) * DM + kk * 32 + g * 8);

    float4 bb[4], lw[4], lb[4];
    #pragma unroll
    for (int mf = 0; mf < 4; ++mf) {
        int c = cg * 64 + mf * 16 + g * 4;
        bb[mf] = *(const float4*)(bo + c);
        lw[mf] = *(const float4*)(lnw + c);
        lb[mf] = *(const float4*)(lnb + c);
    }

    int s0 = blockIdx.x * 16 + sgrp;
    bf16x8 af[8];
    #pragma unroll
    for (int kk = 0; kk < 8; ++kk)
        af[kk] = *(const bf16x8*)(Ab + (size_t)(s0 * 16 + lc) * DM + kk * 32 + g * 8);

    #pragma unroll
    for (int it = 0; it < 8; ++it) {
        int s = s0 + it * 2;
        f32x4 acc[4];
        #pragma unroll
        for (int mf = 0; mf < 4; ++mf) acc[mf] = (f32x4){0.f, 0.f, 0.f, 0.f};
        #pragma unroll
        for (int kk = 0; kk < 8; ++kk)
            #pragma unroll
            for (int mf = 0; mf < 4; ++mf)
                acc[mf] = __builtin_amdgcn_mfma_f32_16x16x32_bf16(wf[mf][kk], af[kk], acc[mf], 0, 0, 0);

        // G frags + h residual loads (issue early)
        ushort4 gf[4];
        #pragma unroll
        for (int mf = 0; mf < 4; ++mf)
            gf[mf] = *(const ushort4*)(G + ((size_t)((s * 4 + cg) * 4 + mf) * 64 + lane) * 4);
        int m = s * 16 + lc;
        int b_ = m >> 14, w_ = (m >> 7) & 127, hh_ = m & 127;
        size_t hrow = ((size_t)((b_ << 14) | (hh_ << 7) | w_)) * DM + cg * 64 + g * 4;
        float4 hv[4];
        #pragma unroll
        for (int mf = 0; mf < 4; ++mf)
            hv[mf] = *(const float4*)(h + hrow + mf * 16);

        if (it < 7) {
            int sn = s + 2;
            #pragma unroll
            for (int kk = 0; kk < 8; ++kk)
                af[kk] = *(const bf16x8*)(Ab + (size_t)(sn * 16 + lc) * DM + kk * 32 + g * 8);
        }

        float v[4][4];
        float s1 = 0.f, s2 = 0.f;
        #pragma unroll
        for (int mf = 0; mf < 4; ++mf) {
            #pragma unroll
            for (int reg = 0; reg < 4; ++reg) {
                float a = acc[mf][reg] + (&bb[mf].x)[reg];
                float gs = bf2f((&gf[mf].x)[reg]);
                float val = fmaf(a, gs, 0.0f) + (&hv[mf].x)[reg];
                v[mf][reg] = val;
                s1 += val;
                s2 += val * val;
            }
        }
        s1 += __shfl_xor(s1, 16);
        s2 += __shfl_xor(s2, 16);
        s1 += __shfl_xor(s1, 32);
        s2 += __shfl_xor(s2, 32);
        if (g == 0) {
            pads[sgrp][lc][cg][0] = s1;
            pads[sgrp][lc][cg][1] = s2;
        }
        __syncthreads();
        float st = 0.f, st2 = 0.f;
        #pragma unroll
        for (int q = 0; q < 4; ++q) {
            st += pads[sgrp][lc][q][0];
            st2 += pads[sgrp][lc][q][1];
        }
        __syncthreads();
        float mean = st * (1.0f / 256.0f);
        float var = st2 * (1.0f / 256.0f) - mean * mean;
        float inv = rsqrtf(var + 1e-5f);
        #pragma unroll
        for (int mf = 0; mf < 4; ++mf) {
            float4 o;
            o.x = (v[mf][0] - mean) * inv * lw[mf].x + lb[mf].x;
            o.y = (v[mf][1] - mean) * inv * lw[mf].y + lb[mf].y;
            o.z = (v[mf][2] - mean) * inv * lw[mf].z + lb[mf].z;
            o.w = (v[mf][3] - mean) * inv * lw[mf].w + lb[mf].w;
            *(float4*)(h + hrow + mf * 16) = o;
        }
    }
}

// ---------------------------------------------------------------------------
// Decoder (unchanged).
// ---------------------------------------------------------------------------
__global__ __launch_bounds__(256) void decode_kernel(
        const float* __restrict__ h, const float* __restrict__ Wd,
        const float* __restrict__ bd, float* __restrict__ out) {
    int pos = blockIdx.x * 4 + (threadIdx.x >> 6);
    int lane = threadIdx.x & 63;
    float s = 0.0f;
    #pragma unroll
    for (int j = 0; j < 4; ++j) {
        int d = j * 64 + lane;
        s += h[(size_t)pos * DM + d] * Wd[d];
    }
    #pragma unroll
    for (int off = 32; off > 0; off >>= 1) s += __shfl_down(s, off);
    if (lane == 0) out[pos] = s + bd[0];
}

// ---------------------------------------------------------------------------
extern "C" void kernel_launch(void* const* d_in, const int* in_sizes, int n_in,
                              void* d_out, int out_size, void* d_ws, size_t ws_size,
                              hipStream_t stream) {
    const float* x       = (const float*)d_in[0];
    const float* grid    = (const float*)d_in[1];
    const float* W_enc   = (const float*)d_in[2];
    const float* b_enc   = (const float*)d_in[3];
    const float* log_dt  = (const float*)d_in[4];
    const float* logA_re = (const float*)d_in[5];
    const float* A_im    = (const float*)d_in[6];
    const float* C_re    = (const float*)d_in[7];
    const float* C_im    = (const float*)d_in[8];
    const float* Dskip   = (const float*)d_in[9];
    const float* W_out   = (const float*)d_in[10];
    const float* b_out   = (const float*)d_in[11];
    const float* ln_w    = (const float*)d_in[12];
    const float* ln_b    = (const float*)d_in[13];
    const float* W_dec   = (const float*)d_in[14];
    const float* b_dec   = (const float*)d_in[15];

    float* ws = (float*)d_ws;
    float*          K_Tp = ws;                                   // 327,680 f
    float*          hbuf = ws + 327680;                          // 16,777,216 f
    unsigned short* T16  = (unsigned short*)(ws + 17104896);     // 16,777,216 bf16
    unsigned short* Abuf = T16 + 16777216;                       // 16,777,216 bf16
    unsigned short* Bt   = (unsigned short*)(ws + 33882112);     // 524,288 bf16
    unsigned short* Gbuf = T16;    // reuse: T16 dead after conv_h, G same size

    hipMemsetAsync(K_Tp, 0, (size_t)8 * KROWS * DM * sizeof(float), stream);
    gen_k_kernel<<<dim3(8 * DM), dim3(128), 0, stream>>>(log_dt, logA_re, A_im,
                                                         C_re, C_im, K_Tp);
    prep_b_kernel<<<dim3(2048), dim3(256), 0, stream>>>(W_out, Bt);
    encode_kernel<<<dim3(2048), dim3(256), 0, stream>>>(x, grid, W_enc, b_enc, hbuf);

    for (int l = 0; l < 4; ++l) {
        const float* Kh = K_Tp + (size_t)(l * 2 + 0) * KROWS * DM;
        const float* Kw = K_Tp + (size_t)(l * 2 + 1) * KROWS * DM;
        const unsigned short* Btl = Bt + (size_t)l * 131072;
        conv_w_kernel<<<dim3(2048), dim3(256), 0, stream>>>(hbuf, T16, Kw);
        conv_h_kernel<<<dim3(2048), dim3(256), 0, stream>>>(T16, Abuf, Kh,
                                                            hbuf, Dskip + (size_t)l * DM);
        gpass_kernel<<<dim3(256), dim3(512), 0, stream>>>(Abuf, Btl,
            b_out + (size_t)l * 512, Gbuf);
        apass_kernel<<<dim3(256), dim3(512), 0, stream>>>(Abuf, Btl, Gbuf, hbuf,
            b_out + (size_t)l * 512, ln_w + (size_t)l * DM, ln_b + (size_t)l * DM);
    }

    decode_kernel<<<dim3(16384), dim3(256), 0, stream>>>(hbuf, W_dec, b_dec,
                                                         (float*)d_out);
}

// Round 4
// 895.434 us; speedup vs baseline: 1.3827x; 1.3827x over previous
//
#include <hip/hip_runtime.h>
#include <math.h>

#define DM 256          // d_model
#define NS 64           // N state
#define SP 128          // spatial H == W
#define KPAD 32         // zero-pad rows in front of kernel (for negative indices)
#define KROWS (KPAD + SP)   // 160

typedef __attribute__((ext_vector_type(8))) short bf16x8;
typedef __attribute__((ext_vector_type(4))) float f32x4;
typedef __attribute__((ext_vector_type(2))) float f32x2;

__device__ __forceinline__ float gelu_f(float x) {
    float x3 = x * x * x;
    return 0.5f * x * (1.0f + tanhf(0.7978845608028654f * (x + 0.044715f * x3)));
}
__device__ __forceinline__ float sigmoid_f(float x) {
    return 1.0f / (1.0f + expf(-x));
}
__device__ __forceinline__ unsigned short f2bf(float f) {   // RNE f32->bf16
    unsigned u = __float_as_uint(f);
    u += 0x7fff + ((u >> 16) & 1);
    return (unsigned short)(u >> 16);
}
__device__ __forceinline__ float bf2f(unsigned short b) {
    return __uint_as_float(((unsigned)b) << 16);
}
// packed 2xfp32 FMA: d = a*b + c  (full-rate on CDNA; needed for 157TF peak)
__device__ __forceinline__ f32x2 pkfma(f32x2 a, f32x2 b, f32x2 c) {
    f32x2 d;
    asm("v_pk_fma_f32 %0, %1, %2, %3" : "=v"(d) : "v"(a), "v"(b), "v"(c));
    return d;
}

// ---------------------------------------------------------------------------
// S4D kernel generation (verified round 1). K_Tp fp32 [la][KROWS][DM].
// ---------------------------------------------------------------------------
__global__ __launch_bounds__(128) void gen_k_kernel(
        const float* __restrict__ log_dt, const float* __restrict__ logA_re,
        const float* __restrict__ A_im,   const float* __restrict__ C_re,
        const float* __restrict__ C_im,   float* __restrict__ K_Tp) {
    int blk = blockIdx.x;
    int d  = blk & (DM - 1);
    int la = blk >> 8;
    int q  = threadIdx.x;
    __shared__ float s_cbr[NS], s_cbi[NS], s_dr[NS], s_di[NS];
    int pbase = (la * DM + d) * NS;
    float dt = expf(log_dt[la * DM + d]);
    if (q < NS) {
        int n = q;
        float ar = -expf(logA_re[pbase + n]);
        float ai = A_im[pbase + n];
        float dr = dt * ar, di = dt * ai;
        float er = expf(dr);
        float sn, cs;
        sincosf(di, &sn, &cs);
        float nr = er * cs - 1.0f, ni = er * sn;
        float inv = 1.0f / (ar * ar + ai * ai);
        float br = (nr * ar + ni * ai) * inv;
        float bi = (ni * ar - nr * ai) * inv;
        float cr = C_re[pbase + n], ci = C_im[pbase + n];
        s_cbr[n] = cr * br - ci * bi;
        s_cbi[n] = cr * bi + ci * br;
        s_dr[n] = dr;
        s_di[n] = di;
    }
    __syncthreads();
    float fq = (float)q;
    float acc = 0.0f;
    for (int n = 0; n < NS; ++n) {
        float pr = expf(s_dr[n] * fq);
        float sn, cs;
        sincosf(s_di[n] * fq, &sn, &cs);
        acc += s_cbr[n] * (pr * cs) - s_cbi[n] * (pr * sn);
    }
    K_Tp[(la * KROWS + KPAD + q) * DM + d] = 2.0f * acc;
}

// ---------------------------------------------------------------------------
// W_out fp32 [l][k=256][n=512]  ->  B_T bf16 [l][n=512][k=256]
// ---------------------------------------------------------------------------
__global__ __launch_bounds__(256) void prep_b_kernel(
        const float* __restrict__ Wo, unsigned short* __restrict__ Bt) {
    int idx = blockIdx.x * 256 + threadIdx.x;
    int l = idx >> 17, rem = idx & 131071, n = rem >> 8, k = rem & 255;
    Bt[idx] = f2bf(Wo[(size_t)l * 131072 + k * 512 + n]);
}

// ---------------------------------------------------------------------------
// Encoder -> bf16 h, packed pair stores.
// ---------------------------------------------------------------------------
__global__ __launch_bounds__(256) void encode_kernel(
        const float* __restrict__ x, const float* __restrict__ g,
        const float* __restrict__ W_enc, const float* __restrict__ b_enc,
        unsigned short* __restrict__ h) {
    int total = 4 * SP * SP * 128;   // channel pairs
    for (int idx = blockIdx.x * blockDim.x + threadIdx.x; idx < total;
         idx += gridDim.x * blockDim.x) {
        int c = (idx & 127) * 2;
        int pos = idx >> 7;
        float xv = x[pos], gv = g[pos];
        float v0 = xv * W_enc[c] + gv * W_enc[DM + c] + b_enc[c];
        float v1 = xv * W_enc[c + 1] + gv * W_enc[DM + c + 1] + b_enc[c + 1];
        unsigned o = (unsigned)f2bf(v0) | ((unsigned)f2bf(v1) << 16);
        *(unsigned*)(h + (size_t)pos * DM + c) = o;
    }
}

// ---------------------------------------------------------------------------
// Causal conv along contiguous axis. Block = 1 row (512 blocks), 256 threads:
// half = tid>>7 (tiles {0,3} / {1,2} - balanced 5 j-blocks each),
// c2 = tid&127 -> channel pair, packed v_pk_fma_f32.
// K taps preloaded 16-deep so no global load sits on the FMA chain.
// MODE 0: in=h bf16 (b,hh,w,d) -> out T bf16 transposed (b,w,hh,d).
// MODE 1: in=T bf16 (b,w,hh,d) -> A=gelu(conv + h*Dskip) bf16, m=(b,w,hh).
// ---------------------------------------------------------------------------
template <int MODE>
__global__ __launch_bounds__(256, 2) void conv_kernel(
        const unsigned short* __restrict__ in, unsigned short* __restrict__ out,
        const float* __restrict__ KT, const unsigned short* __restrict__ h,
        const float* __restrict__ Dsk) {
    int r = blockIdx.x;                  // b*128 + rr
    int tid = threadIdx.x;
    int half = tid >> 7, c2 = tid & 127;
    int c = c2 * 2;
    const unsigned short* row = in + (size_t)r * (SP * DM) + c;
    int b = r >> 7, rr = r & 127;
    f32x2 dk2 = (f32x2){0.f, 0.f};
    if (MODE == 1) { dk2[0] = Dsk[c]; dk2[1] = Dsk[c + 1]; }

    #pragma unroll
    for (int ti = 0; ti < 2; ++ti) {
        int t = half ? (1 + ti) : (3 * ti);
        int w0 = t * 32;
        f32x2 acc[32], kreg[32];
        #pragma unroll
        for (int i = 0; i < 32; ++i) acc[i] = (f32x2){0.f, 0.f};
        const float* kbase = KT + (size_t)(KPAD + w0) * DM + c;
        #pragma unroll
        for (int s = 0; s < 32; ++s) kreg[s] = *(const f32x2*)(kbase + (size_t)s * DM);

        for (int jb = 0; jb <= t; ++jb) {
            const float* kb = KT + (size_t)(KPAD + w0 - jb * 32 - 1) * DM + c;
            const unsigned short* ub = row + (size_t)jb * 32 * DM;
            #pragma unroll
            for (int hb = 0; hb < 2; ++hb) {
                f32x2 kn2[16];
                #pragma unroll
                for (int q = 0; q < 16; ++q)
                    kn2[q] = *(const f32x2*)(kb - (size_t)(hb * 16 + q) * DM);
                #pragma unroll
                for (int jj2 = 0; jj2 < 16; ++jj2) {
                    int jj = hb * 16 + jj2;
                    unsigned us = *(const unsigned*)(ub + (size_t)jj * DM);
                    f32x2 u2;
                    u2[0] = __uint_as_float(us << 16);
                    u2[1] = __uint_as_float(us & 0xffff0000u);
                    #pragma unroll
                    for (int i = 0; i < 32; ++i)
                        acc[i] = pkfma(kreg[(i - jj) & 31], u2, acc[i]);
                    kreg[(31 - jj) & 31] = kn2[jj2];
                }
            }
        }

        if (MODE == 0) {
            #pragma unroll
            for (int i = 0; i < 32; ++i) {
                unsigned o = (unsigned)f2bf(acc[i][0]) | ((unsigned)f2bf(acc[i][1]) << 16);
                *(unsigned*)(out + ((size_t)((b << 7) | (w0 + i)) * SP + rr) * DM + c) = o;
            }
        } else {
            #pragma unroll
            for (int i = 0; i < 32; ++i) {
                int hh = w0 + i;
                unsigned hu = *(const unsigned*)(h + ((size_t)((b << 14) | (hh << 7) | rr)) * DM + c);
                float v0 = gelu_f(fmaf(__uint_as_float(hu << 16), dk2[0], acc[i][0]));
                float v1 = gelu_f(fmaf(__uint_as_float(hu & 0xffff0000u), dk2[1], acc[i][1]));
                unsigned o = (unsigned)f2bf(v0) | ((unsigned)f2bf(v1) << 16);
                *(unsigned*)(out + ((size_t)r * SP + hh) * DM + c) = o;
            }
        }
    }
}

// ---------------------------------------------------------------------------
// Fused GLU: 8 waves = 4 a-waves (cols cg*64..) + 4 g-waves (cols 256+cg*64..),
// each with persistent W frags (128 VGPR). Per strip (16 rows): all waves MFMA;
// g-waves write sigmoid(g+bias) to padded LDS; a-waves do GLU + residual + LN,
// h updated in place (bf16). Strip prefetch of A frags after MFMA.
// D mapping (verified r3): actrow = lane&15, wcol = (lane>>4)*4+reg per mf.
// ---------------------------------------------------------------------------
__global__ __launch_bounds__(512, 2) void glu_kernel(
        const unsigned short* __restrict__ Ab, const unsigned short* __restrict__ Bt,
        unsigned short* __restrict__ h,
        const float* __restrict__ bo, const float* __restrict__ lnw,
        const float* __restrict__ lnb) {
    __shared__ float gate[16][257];
    __shared__ float pads[16][4][2];
    int tid = threadIdx.x;
    int lane = tid & 63, wv = tid >> 6;
    int isg = wv >> 2;             // 0 = a-half, 1 = g-half
    int cg = wv & 3;
    int lc = lane & 15, g = lane >> 4;

    bf16x8 wf[4][8];
    #pragma unroll
    for (int mf = 0; mf < 4; ++mf)
        #pragma unroll
        for (int kk = 0; kk < 8; ++kk)
            wf[mf][kk] = *(const bf16x8*)(Bt + (size_t)(isg * 256 + cg * 64 + mf * 16 + lc) * DM + kk * 32 + g * 8);

    float4 bb[4];
    #pragma unroll
    for (int mf = 0; mf < 4; ++mf)
        bb[mf] = *(const float4*)(bo + isg * 256 + cg * 64 + mf * 16 + g * 4);

    int s = blockIdx.x * 16;
    bf16x8 af[8];
    #pragma unroll
    for (int kk = 0; kk < 8; ++kk)
        af[kk] = *(const bf16x8*)(Ab + (size_t)(s * 16 + lc) * DM + kk * 32 + g * 8);

    for (int it = 0; it < 16; ++it) {
        f32x4 acc[4];
        #pragma unroll
        for (int mf = 0; mf < 4; ++mf) acc[mf] = (f32x4){0.f, 0.f, 0.f, 0.f};
        #pragma unroll
        for (int kk = 0; kk < 8; ++kk)
            #pragma unroll
            for (int mf = 0; mf < 4; ++mf)
                acc[mf] = __builtin_amdgcn_mfma_f32_16x16x32_bf16(wf[mf][kk], af[kk], acc[mf], 0, 0, 0);

        if (isg) {
            #pragma unroll
            for (int mf = 0; mf < 4; ++mf) {
                int cb = cg * 64 + mf * 16 + g * 4;
                #pragma unroll
                for (int reg = 0; reg < 4; ++reg)
                    gate[lc][cb + reg] = sigmoid_f(acc[mf][reg] + (&bb[mf].x)[reg]);
            }
        }
        // prefetch next strip's A frags (flies during epilogue)
        if (it < 15) {
            #pragma unroll
            for (int kk = 0; kk < 8; ++kk)
                af[kk] = *(const bf16x8*)(Ab + (size_t)((s + 1) * 16 + lc) * DM + kk * 32 + g * 8);
        }
        __syncthreads();   // gate visible

        int m = s * 16 + lc;
        int b_ = m >> 14, w_ = (m >> 7) & 127, hh_ = m & 127;
        size_t hrow = ((size_t)((b_ << 14) | (hh_ << 7) | w_)) * DM + cg * 64 + g * 4;
        float v[4][4];
        float4 lw[4], lb[4];
        if (!isg) {
            uint2 hv[4];
            #pragma unroll
            for (int mf = 0; mf < 4; ++mf)
                hv[mf] = *(const uint2*)(h + hrow + mf * 16);
            float s1 = 0.f, sq = 0.f;
            #pragma unroll
            for (int mf = 0; mf < 4; ++mf) {
                int cb = cg * 64 + mf * 16 + g * 4;
                lw[mf] = *(const float4*)(lnw + cb);
                lb[mf] = *(const float4*)(lnb + cb);
                float hr[4];
                hr[0] = __uint_as_float(hv[mf].x << 16);
                hr[1] = __uint_as_float(hv[mf].x & 0xffff0000u);
                hr[2] = __uint_as_float(hv[mf].y << 16);
                hr[3] = __uint_as_float(hv[mf].y & 0xffff0000u);
                #pragma unroll
                for (int reg = 0; reg < 4; ++reg) {
                    float a = acc[mf][reg] + (&bb[mf].x)[reg];
                    float val = a * gate[lc][cb + reg] + hr[reg];
                    v[mf][reg] = val;
                    s1 += val;
                    sq += val * val;
                }
            }
            s1 += __shfl_xor(s1, 16); sq += __shfl_xor(sq, 16);
            s1 += __shfl_xor(s1, 32); sq += __shfl_xor(sq, 32);
            if (g == 0) { pads[lc][cg][0] = s1; pads[lc][cg][1] = sq; }
        }
        __syncthreads();   // pads visible
        if (!isg) {
            float st = 0.f, st2 = 0.f;
            #pragma unroll
            for (int q = 0; q < 4; ++q) { st += pads[lc][q][0]; st2 += pads[lc][q][1]; }
            float mean = st * (1.0f / 256.0f);
            float var = st2 * (1.0f / 256.0f) - mean * mean;
            float inv = rsqrtf(var + 1e-5f);
            #pragma unroll
            for (int mf = 0; mf < 4; ++mf) {
                float o0 = (v[mf][0] - mean) * inv * lw[mf].x + lb[mf].x;
                float o1 = (v[mf][1] - mean) * inv * lw[mf].y + lb[mf].y;
                float o2 = (v[mf][2] - mean) * inv * lw[mf].z + lb[mf].z;
                float o3 = (v[mf][3] - mean) * inv * lw[mf].w + lb[mf].w;
                uint2 ov;
                ov.x = (unsigned)f2bf(o0) | ((unsigned)f2bf(o1) << 16);
                ov.y = (unsigned)f2bf(o2) | ((unsigned)f2bf(o3) << 16);
                *(uint2*)(h + hrow + mf * 16) = ov;
            }
        }
        ++s;
    }
}

// ---------------------------------------------------------------------------
// Decoder: bf16 h in.
// ---------------------------------------------------------------------------
__global__ __launch_bounds__(256) void decode_kernel(
        const unsigned short* __restrict__ h, const float* __restrict__ Wd,
        const float* __restrict__ bd, float* __restrict__ out) {
    int pos = blockIdx.x * 4 + (threadIdx.x >> 6);
    int lane = threadIdx.x & 63;
    float s = 0.0f;
    #pragma unroll
    for (int j = 0; j < 4; ++j) {
        int d = j * 64 + lane;
        s += bf2f(h[(size_t)pos * DM + d]) * Wd[d];
    }
    #pragma unroll
    for (int off = 32; off > 0; off >>= 1) s += __shfl_down(s, off);
    if (lane == 0) out[pos] = s + bd[0];
}

// ---------------------------------------------------------------------------
extern "C" void kernel_launch(void* const* d_in, const int* in_sizes, int n_in,
                              void* d_out, int out_size, void* d_ws, size_t ws_size,
                              hipStream_t stream) {
    const float* x       = (const float*)d_in[0];
    const float* grid    = (const float*)d_in[1];
    const float* W_enc   = (const float*)d_in[2];
    const float* b_enc   = (const float*)d_in[3];
    const float* log_dt  = (const float*)d_in[4];
    const float* logA_re = (const float*)d_in[5];
    const float* A_im    = (const float*)d_in[6];
    const float* C_re    = (const float*)d_in[7];
    const float* C_im    = (const float*)d_in[8];
    const float* Dskip   = (const float*)d_in[9];
    const float* W_out   = (const float*)d_in[10];
    const float* b_out   = (const float*)d_in[11];
    const float* ln_w    = (const float*)d_in[12];
    const float* ln_b    = (const float*)d_in[13];
    const float* W_dec   = (const float*)d_in[14];
    const float* b_dec   = (const float*)d_in[15];

    char* base = (char*)d_ws;
    float*          K_Tp = (float*)base;                              // 1,310,720 B
    unsigned short* hbuf = (unsigned short*)(base + 1310720);         // 33,554,432 B
    unsigned short* T16  = (unsigned short*)(base + 34865152);        // 33,554,432 B
    unsigned short* Abuf = (unsigned short*)(base + 68419584);        // 33,554,432 B
    unsigned short* Bt   = (unsigned short*)(base + 101974016);       // 1,048,576 B

    hipMemsetAsync(K_Tp, 0, (size_t)8 * KROWS * DM * sizeof(float), stream);
    gen_k_kernel<<<dim3(8 * DM), dim3(128), 0, stream>>>(log_dt, logA_re, A_im,
                                                         C_re, C_im, K_Tp);
    prep_b_kernel<<<dim3(2048), dim3(256), 0, stream>>>(W_out, Bt);
    encode_kernel<<<dim3(2048), dim3(256), 0, stream>>>(x, grid, W_enc, b_enc, hbuf);

    for (int l = 0; l < 4; ++l) {
        const float* Kh = K_Tp + (size_t)(l * 2 + 0) * KROWS * DM;
        const float* Kw = K_Tp + (size_t)(l * 2 + 1) * KROWS * DM;
        const unsigned short* Btl = Bt + (size_t)l * 131072;
        conv_kernel<0><<<dim3(512), dim3(256), 0, stream>>>(hbuf, T16, Kw,
                                                            (const unsigned short*)nullptr, (const float*)nullptr);
        conv_kernel<1><<<dim3(512), dim3(256), 0, stream>>>(T16, Abuf, Kh,
                                                            hbuf, Dskip + (size_t)l * DM);
        glu_kernel<<<dim3(256), dim3(512), 0, stream>>>(Abuf, Btl, hbuf,
            b_out + (size_t)l * 512, ln_w + (size_t)l * DM, ln_b + (size_t)l * DM);
    }

    decode_kernel<<<dim3(16384), dim3(256), 0, stream>>>(hbuf, W_dec, b_dec,
                                                         (float*)d_out);
}

// Round 5
// 841.835 us; speedup vs baseline: 1.4707x; 1.0637x over previous
//
#include <hip/hip_runtime.h>
#include <math.h>

#define DM 256          // d_model
#define NS 64           // N state
#define SP 128          // spatial H == W
#define KPAD 32         // zero-pad rows in front of kernel (for negative indices)
#define KROWS (KPAD + SP)   // 160

typedef __attribute__((ext_vector_type(8))) short bf16x8;
typedef __attribute__((ext_vector_type(4))) float f32x4;
typedef __attribute__((ext_vector_type(2))) float f32x2;

__device__ __forceinline__ float gelu_f(float x) {
    float x3 = x * x * x;
    return 0.5f * x * (1.0f + tanhf(0.7978845608028654f * (x + 0.044715f * x3)));
}
__device__ __forceinline__ float sigmoid_f(float x) {
    return 1.0f / (1.0f + expf(-x));
}
__device__ __forceinline__ unsigned short f2bf(float f) {   // RNE f32->bf16
    unsigned u = __float_as_uint(f);
    u += 0x7fff + ((u >> 16) & 1);
    return (unsigned short)(u >> 16);
}
__device__ __forceinline__ float bf2f(unsigned short b) {
    return __uint_as_float(((unsigned)b) << 16);
}
// packed 2xfp32 FMA (same throughput as scalar fma, halves instruction count)
__device__ __forceinline__ f32x2 pkfma(f32x2 a, f32x2 b, f32x2 c) {
    f32x2 d;
    asm("v_pk_fma_f32 %0, %1, %2, %3" : "=v"(d) : "v"(a), "v"(b), "v"(c));
    return d;
}

// ---------------------------------------------------------------------------
// S4D kernel generation (verified round 1). K_Tp fp32 [la][KROWS][DM].
// ---------------------------------------------------------------------------
__global__ __launch_bounds__(128) void gen_k_kernel(
        const float* __restrict__ log_dt, const float* __restrict__ logA_re,
        const float* __restrict__ A_im,   const float* __restrict__ C_re,
        const float* __restrict__ C_im,   float* __restrict__ K_Tp) {
    int blk = blockIdx.x;
    int d  = blk & (DM - 1);
    int la = blk >> 8;
    int q  = threadIdx.x;
    __shared__ float s_cbr[NS], s_cbi[NS], s_dr[NS], s_di[NS];
    int pbase = (la * DM + d) * NS;
    float dt = expf(log_dt[la * DM + d]);
    if (q < NS) {
        int n = q;
        float ar = -expf(logA_re[pbase + n]);
        float ai = A_im[pbase + n];
        float dr = dt * ar, di = dt * ai;
        float er = expf(dr);
        float sn, cs;
        sincosf(di, &sn, &cs);
        float nr = er * cs - 1.0f, ni = er * sn;
        float inv = 1.0f / (ar * ar + ai * ai);
        float br = (nr * ar + ni * ai) * inv;
        float bi = (ni * ar - nr * ai) * inv;
        float cr = C_re[pbase + n], ci = C_im[pbase + n];
        s_cbr[n] = cr * br - ci * bi;
        s_cbi[n] = cr * bi + ci * br;
        s_dr[n] = dr;
        s_di[n] = di;
    }
    __syncthreads();
    float fq = (float)q;
    float acc = 0.0f;
    for (int n = 0; n < NS; ++n) {
        float pr = expf(s_dr[n] * fq);
        float sn, cs;
        sincosf(s_di[n] * fq, &sn, &cs);
        acc += s_cbr[n] * (pr * cs) - s_cbi[n] * (pr * sn);
    }
    K_Tp[(la * KROWS + KPAD + q) * DM + d] = 2.0f * acc;
}

// ---------------------------------------------------------------------------
// W_out fp32 [l][k=256][n=512]  ->  B_T bf16 [l][n=512][k=256]
// ---------------------------------------------------------------------------
__global__ __launch_bounds__(256) void prep_b_kernel(
        const float* __restrict__ Wo, unsigned short* __restrict__ Bt) {
    int idx = blockIdx.x * 256 + threadIdx.x;
    int l = idx >> 17, rem = idx & 131071, n = rem >> 8, k = rem & 255;
    Bt[idx] = f2bf(Wo[(size_t)l * 131072 + k * 512 + n]);
}

// ---------------------------------------------------------------------------
// Encoder -> bf16 h, packed pair stores.
// ---------------------------------------------------------------------------
__global__ __launch_bounds__(256) void encode_kernel(
        const float* __restrict__ x, const float* __restrict__ g,
        const float* __restrict__ W_enc, const float* __restrict__ b_enc,
        unsigned short* __restrict__ h) {
    int total = 4 * SP * SP * 128;   // channel pairs
    for (int idx = blockIdx.x * blockDim.x + threadIdx.x; idx < total;
         idx += gridDim.x * blockDim.x) {
        int c = (idx & 127) * 2;
        int pos = idx >> 7;
        float xv = x[pos], gv = g[pos];
        float v0 = xv * W_enc[c] + gv * W_enc[DM + c] + b_enc[c];
        float v1 = xv * W_enc[c + 1] + gv * W_enc[DM + c + 1] + b_enc[c + 1];
        unsigned o = (unsigned)f2bf(v0) | ((unsigned)f2bf(v1) << 16);
        *(unsigned*)(h + (size_t)pos * DM + c) = o;
    }
}

// ---------------------------------------------------------------------------
// Causal conv (verified round 4, unchanged).
// MODE 0: in=h bf16 (b,hh,w,d) -> out T bf16 transposed (b,w,hh,d).
// MODE 1: in=T bf16 (b,w,hh,d) -> A=gelu(conv + h*Dskip) bf16, m=(b,w,hh).
// ---------------------------------------------------------------------------
template <int MODE>
__global__ __launch_bounds__(256, 2) void conv_kernel(
        const unsigned short* __restrict__ in, unsigned short* __restrict__ out,
        const float* __restrict__ KT, const unsigned short* __restrict__ h,
        const float* __restrict__ Dsk) {
    int r = blockIdx.x;                  // b*128 + rr
    int tid = threadIdx.x;
    int half = tid >> 7, c2 = tid & 127;
    int c = c2 * 2;
    const unsigned short* row = in + (size_t)r * (SP * DM) + c;
    int b = r >> 7, rr = r & 127;
    f32x2 dk2 = (f32x2){0.f, 0.f};
    if (MODE == 1) { dk2[0] = Dsk[c]; dk2[1] = Dsk[c + 1]; }

    #pragma unroll
    for (int ti = 0; ti < 2; ++ti) {
        int t = half ? (1 + ti) : (3 * ti);
        int w0 = t * 32;
        f32x2 acc[32], kreg[32];
        #pragma unroll
        for (int i = 0; i < 32; ++i) acc[i] = (f32x2){0.f, 0.f};
        const float* kbase = KT + (size_t)(KPAD + w0) * DM + c;
        #pragma unroll
        for (int s = 0; s < 32; ++s) kreg[s] = *(const f32x2*)(kbase + (size_t)s * DM);

        for (int jb = 0; jb <= t; ++jb) {
            const float* kb = KT + (size_t)(KPAD + w0 - jb * 32 - 1) * DM + c;
            const unsigned short* ub = row + (size_t)jb * 32 * DM;
            #pragma unroll
            for (int hb = 0; hb < 2; ++hb) {
                f32x2 kn2[16];
                #pragma unroll
                for (int q = 0; q < 16; ++q)
                    kn2[q] = *(const f32x2*)(kb - (size_t)(hb * 16 + q) * DM);
                #pragma unroll
                for (int jj2 = 0; jj2 < 16; ++jj2) {
                    int jj = hb * 16 + jj2;
                    unsigned us = *(const unsigned*)(ub + (size_t)jj * DM);
                    f32x2 u2;
                    u2[0] = __uint_as_float(us << 16);
                    u2[1] = __uint_as_float(us & 0xffff0000u);
                    #pragma unroll
                    for (int i = 0; i < 32; ++i)
                        acc[i] = pkfma(kreg[(i - jj) & 31], u2, acc[i]);
                    kreg[(31 - jj) & 31] = kn2[jj2];
                }
            }
        }

        if (MODE == 0) {
            #pragma unroll
            for (int i = 0; i < 32; ++i) {
                unsigned o = (unsigned)f2bf(acc[i][0]) | ((unsigned)f2bf(acc[i][1]) << 16);
                *(unsigned*)(out + ((size_t)((b << 7) | (w0 + i)) * SP + rr) * DM + c) = o;
            }
        } else {
            #pragma unroll
            for (int i = 0; i < 32; ++i) {
                int hh = w0 + i;
                unsigned hu = *(const unsigned*)(h + ((size_t)((b << 14) | (hh << 7) | rr)) * DM + c);
                float v0 = gelu_f(fmaf(__uint_as_float(hu << 16), dk2[0], acc[i][0]));
                float v1 = gelu_f(fmaf(__uint_as_float(hu & 0xffff0000u), dk2[1], acc[i][1]));
                unsigned o = (unsigned)f2bf(v0) | ((unsigned)f2bf(v1) << 16);
                *(unsigned*)(out + ((size_t)r * SP + hh) * DM + c) = o;
            }
        }
    }
}

// ---------------------------------------------------------------------------
// GLU GEMM, barrier-free & LDS-free: hp = (A@W_a + b_a) * sigmoid(A@W_g + b_g)
//                                         + h  (bf16, pos-order)
// 8 waves/block; wave wv holds persistent W frags for a-cols [wv*32,+32) AND
// g-cols [256+wv*32,+32) (128 VGPR). Operand-swapped MFMA (verified r4):
// D act-row = lane&15 (lc), w-col = cf*16 + (lane>>4)*4 + reg -> residual and
// store are contiguous uint2 per lane. Block = 128 rows = 8 strips of 16.
// af[kk] reloaded for strip s+1 right after its last use in strip s (zero-cost
// software pipeline). No __syncthreads anywhere.
// ---------------------------------------------------------------------------
__global__ __launch_bounds__(512, 1) void glu_kernel(
        const unsigned short* __restrict__ Ab, const unsigned short* __restrict__ Bt,
        const unsigned short* __restrict__ h, unsigned short* __restrict__ hp,
        const float* __restrict__ bo) {
    int tid = threadIdx.x;
    int lane = tid & 63, wv = tid >> 6;
    int lc = lane & 15, g = lane >> 4;
    int m0 = blockIdx.x * 128;

    // persistent W frags: cf 0,1 = a-cols, cf 2,3 = matching g-cols
    bf16x8 wf[4][8];
    #pragma unroll
    for (int cf = 0; cf < 4; ++cf) {
        int colb = (cf < 2) ? (wv * 32 + cf * 16) : (256 + wv * 32 + (cf - 2) * 16);
        #pragma unroll
        for (int kk = 0; kk < 8; ++kk)
            wf[cf][kk] = *(const bf16x8*)(Bt + (size_t)(colb + lc) * DM + kk * 32 + g * 8);
    }
    float4 ba[2], bg[2];
    #pragma unroll
    for (int cf = 0; cf < 2; ++cf) {
        ba[cf] = *(const float4*)(bo + wv * 32 + cf * 16 + g * 4);
        bg[cf] = *(const float4*)(bo + 256 + wv * 32 + cf * 16 + g * 4);
    }

    bf16x8 af[8];
    #pragma unroll
    for (int kk = 0; kk < 8; ++kk)
        af[kk] = *(const bf16x8*)(Ab + (size_t)(m0 + lc) * DM + kk * 32 + g * 8);

    #pragma unroll
    for (int s = 0; s < 8; ++s) {
        int m = m0 + s * 16 + lc;
        int b_ = m >> 14, w_ = (m >> 7) & 127, hh_ = m & 127;
        size_t pbase = ((size_t)((b_ << 14) | (hh_ << 7) | w_)) * DM + wv * 32 + g * 4;
        // residual loads issued early (hidden under MFMA)
        uint2 hv0 = *(const uint2*)(h + pbase);
        uint2 hv1 = *(const uint2*)(h + pbase + 16);

        f32x4 acc0 = (f32x4){0.f, 0.f, 0.f, 0.f};
        f32x4 acc1 = acc0, acc2 = acc0, acc3 = acc0;
        #pragma unroll
        for (int kk = 0; kk < 8; ++kk) {
            acc0 = __builtin_amdgcn_mfma_f32_16x16x32_bf16(wf[0][kk], af[kk], acc0, 0, 0, 0);
            acc1 = __builtin_amdgcn_mfma_f32_16x16x32_bf16(wf[1][kk], af[kk], acc1, 0, 0, 0);
            acc2 = __builtin_amdgcn_mfma_f32_16x16x32_bf16(wf[2][kk], af[kk], acc2, 0, 0, 0);
            acc3 = __builtin_amdgcn_mfma_f32_16x16x32_bf16(wf[3][kk], af[kk], acc3, 0, 0, 0);
            if (s < 7)   // reload for next strip right after last use this strip
                af[kk] = *(const bf16x8*)(Ab + (size_t)(m0 + (s + 1) * 16 + lc) * DM + kk * 32 + g * 8);
        }

        // GLU + residual, bf16 store (pos-order)
        float hr0[4], hr1[4];
        hr0[0] = __uint_as_float(hv0.x << 16);
        hr0[1] = __uint_as_float(hv0.x & 0xffff0000u);
        hr0[2] = __uint_as_float(hv0.y << 16);
        hr0[3] = __uint_as_float(hv0.y & 0xffff0000u);
        hr1[0] = __uint_as_float(hv1.x << 16);
        hr1[1] = __uint_as_float(hv1.x & 0xffff0000u);
        hr1[2] = __uint_as_float(hv1.y << 16);
        hr1[3] = __uint_as_float(hv1.y & 0xffff0000u);
        float o0[4], o1[4];
        #pragma unroll
        for (int reg = 0; reg < 4; ++reg) {
            o0[reg] = (acc0[reg] + (&ba[0].x)[reg]) * sigmoid_f(acc2[reg] + (&bg[0].x)[reg]) + hr0[reg];
            o1[reg] = (acc1[reg] + (&ba[1].x)[reg]) * sigmoid_f(acc3[reg] + (&bg[1].x)[reg]) + hr1[reg];
        }
        uint2 ov0, ov1;
        ov0.x = (unsigned)f2bf(o0[0]) | ((unsigned)f2bf(o0[1]) << 16);
        ov0.y = (unsigned)f2bf(o0[2]) | ((unsigned)f2bf(o0[3]) << 16);
        ov1.x = (unsigned)f2bf(o1[0]) | ((unsigned)f2bf(o1[1]) << 16);
        ov1.y = (unsigned)f2bf(o1[2]) | ((unsigned)f2bf(o1[3]) << 16);
        *(uint2*)(hp + pbase) = ov0;
        *(uint2*)(hp + pbase + 16) = ov1;
    }
}

// ---------------------------------------------------------------------------
// LayerNorm: h = LN(hp) (bf16 -> bf16, pos-order). Wave = 1 row, lane = 4 ch.
// ---------------------------------------------------------------------------
__global__ __launch_bounds__(256) void ln_kernel(
        const unsigned short* __restrict__ hp, unsigned short* __restrict__ h,
        const float* __restrict__ lnw, const float* __restrict__ lnb) {
    int pos = blockIdx.x * 4 + (threadIdx.x >> 6);
    int lane = threadIdx.x & 63;
    size_t base = (size_t)pos * DM + lane * 4;
    uint2 hv = *(const uint2*)(hp + base);
    float v[4];
    v[0] = __uint_as_float(hv.x << 16);
    v[1] = __uint_as_float(hv.x & 0xffff0000u);
    v[2] = __uint_as_float(hv.y << 16);
    v[3] = __uint_as_float(hv.y & 0xffff0000u);
    float s1 = v[0] + v[1] + v[2] + v[3];
    float s2 = v[0] * v[0] + v[1] * v[1] + v[2] * v[2] + v[3] * v[3];
    #pragma unroll
    for (int off = 1; off < 64; off <<= 1) {
        s1 += __shfl_xor(s1, off);
        s2 += __shfl_xor(s2, off);
    }
    float mean = s1 * (1.0f / 256.0f);
    float var = s2 * (1.0f / 256.0f) - mean * mean;
    float inv = rsqrtf(var + 1e-5f);
    float4 w4 = *(const float4*)(lnw + lane * 4);
    float4 b4 = *(const float4*)(lnb + lane * 4);
    float o0 = (v[0] - mean) * inv * w4.x + b4.x;
    float o1 = (v[1] - mean) * inv * w4.y + b4.y;
    float o2 = (v[2] - mean) * inv * w4.z + b4.z;
    float o3 = (v[3] - mean) * inv * w4.w + b4.w;
    uint2 ov;
    ov.x = (unsigned)f2bf(o0) | ((unsigned)f2bf(o1) << 16);
    ov.y = (unsigned)f2bf(o2) | ((unsigned)f2bf(o3) << 16);
    *(uint2*)(h + base) = ov;
}

// ---------------------------------------------------------------------------
// Decoder: bf16 h in.
// ---------------------------------------------------------------------------
__global__ __launch_bounds__(256) void decode_kernel(
        const unsigned short* __restrict__ h, const float* __restrict__ Wd,
        const float* __restrict__ bd, float* __restrict__ out) {
    int pos = blockIdx.x * 4 + (threadIdx.x >> 6);
    int lane = threadIdx.x & 63;
    float s = 0.0f;
    #pragma unroll
    for (int j = 0; j < 4; ++j) {
        int d = j * 64 + lane;
        s += bf2f(h[(size_t)pos * DM + d]) * Wd[d];
    }
    #pragma unroll
    for (int off = 32; off > 0; off >>= 1) s += __shfl_down(s, off);
    if (lane == 0) out[pos] = s + bd[0];
}

// ---------------------------------------------------------------------------
extern "C" void kernel_launch(void* const* d_in, const int* in_sizes, int n_in,
                              void* d_out, int out_size, void* d_ws, size_t ws_size,
                              hipStream_t stream) {
    const float* x       = (const float*)d_in[0];
    const float* grid    = (const float*)d_in[1];
    const float* W_enc   = (const float*)d_in[2];
    const float* b_enc   = (const float*)d_in[3];
    const float* log_dt  = (const float*)d_in[4];
    const float* logA_re = (const float*)d_in[5];
    const float* A_im    = (const float*)d_in[6];
    const float* C_re    = (const float*)d_in[7];
    const float* C_im    = (const float*)d_in[8];
    const float* Dskip   = (const float*)d_in[9];
    const float* W_out   = (const float*)d_in[10];
    const float* b_out   = (const float*)d_in[11];
    const float* ln_w    = (const float*)d_in[12];
    const float* ln_b    = (const float*)d_in[13];
    const float* W_dec   = (const float*)d_in[14];
    const float* b_dec   = (const float*)d_in[15];

    char* base = (char*)d_ws;
    float*          K_Tp = (float*)base;                              // 1,310,720 B
    unsigned short* hbuf = (unsigned short*)(base + 1310720);         // 33,554,432 B
    unsigned short* T16  = (unsigned short*)(base + 34865152);        // 33,554,432 B
    unsigned short* Abuf = (unsigned short*)(base + 68419584);        // 33,554,432 B
    unsigned short* Bt   = (unsigned short*)(base + 101974016);       // 1,048,576 B
    unsigned short* hp   = T16;    // reuse: T16 dead after conv_h

    hipMemsetAsync(K_Tp, 0, (size_t)8 * KROWS * DM * sizeof(float), stream);
    gen_k_kernel<<<dim3(8 * DM), dim3(128), 0, stream>>>(log_dt, logA_re, A_im,
                                                         C_re, C_im, K_Tp);
    prep_b_kernel<<<dim3(2048), dim3(256), 0, stream>>>(W_out, Bt);
    encode_kernel<<<dim3(2048), dim3(256), 0, stream>>>(x, grid, W_enc, b_enc, hbuf);

    for (int l = 0; l < 4; ++l) {
        const float* Kh = K_Tp + (size_t)(l * 2 + 0) * KROWS * DM;
        const float* Kw = K_Tp + (size_t)(l * 2 + 1) * KROWS * DM;
        const unsigned short* Btl = Bt + (size_t)l * 131072;
        conv_kernel<0><<<dim3(512), dim3(256), 0, stream>>>(hbuf, T16, Kw,
                                                            (const unsigned short*)nullptr, (const float*)nullptr);
        conv_kernel<1><<<dim3(512), dim3(256), 0, stream>>>(T16, Abuf, Kh,
                                                            hbuf, Dskip + (size_t)l * DM);
        glu_kernel<<<dim3(512), dim3(512), 0, stream>>>(Abuf, Btl, hbuf, hp,
            b_out + (size_t)l * 512);
        ln_kernel<<<dim3(16384), dim3(256), 0, stream>>>(hp, hbuf,
            ln_w + (size_t)l * DM, ln_b + (size_t)l * DM);
    }

    decode_kernel<<<dim3(16384), dim3(256), 0, stream>>>(hbuf, W_dec, b_dec,
                                                         (float*)d_out);
}